// Round 8
// baseline (7858.807 us; speedup 1.0000x reference)
//
#include <hip/hip_runtime.h>
#include <hip/hip_cooperative_groups.h>
#include <math.h>

namespace cg = cooperative_groups;
typedef double f64;
#define HDIM 64
#define NNODES 1024
#define NROWS 2048
#define RPB 16       // rows per block
#define NBLK 128
#define NTHR 512

struct Params {
  const float *x, *fw, *fb, *g_in_w, *g_in_b, *g_tr_w, *g_tr_b, *g_a;
  const float *w_ih, *w_hh, *b_ih, *b_hh, *ffn_w, *ffn_b, *ffn_ow, *ffn_ob;
  f64 *h1a, *h1b, *ssa, *sda, *ssb, *sdb, *w_ihT, *w_hhT;
  float* dout;
};

__device__ __forceinline__ f64 wredsum64(f64 v){
#pragma unroll
  for(int o=32;o>0;o>>=1) v += __shfl_xor(v,o);
  return v;
}

// two-stage score, same op-order as the absmax-0 lineage
__device__ __forceinline__ void s_twostage64(const f64* ldsrow,
    const float* __restrict__ g_tr_w, const float* __restrict__ g_tr_b,
    const float* __restrict__ g_a, int h, f64& s_src, f64& s_dst){
  f64 t = (f64)g_tr_b[h];
  for(int c=0;c<HDIM;c++) t = fma(ldsrow[c], (f64)g_tr_w[c*HDIM+h], t);
  s_src = wredsum64(t*(f64)g_a[h]);
  s_dst = wredsum64(t*(f64)g_a[HDIM+h]);
}

// One GAT aggregation: rows yA=2*wave, yB=2*wave+1 of the block's 16 rows.
// Returns agg/ws + residual for both rows. Inner loop identical to R5 (absmax 0).
__device__ __forceinline__ void gat_iter(
    const f64* __restrict__ h1_in, const f64* __restrict__ ss_in,
    const f64* __restrict__ sd_in,
    f64* htile, f64* wbuf, f64* lds_m, f64* lds_sd, f64* lds_ws, f64* red,
    int tid, int wave, int h, int batch, long gr0,
    f64& outA, f64& outB)
{
  const f64* sb = ss_in + (long)batch*NNODES;
  // batch max of s_src (exact row max via monotonicity)
  f64 mx = -1e300;
  for(int j=tid;j<NNODES;j+=NTHR) mx = fmax(mx, sb[j]);
#pragma unroll
  for(int o=32;o>0;o>>=1) mx = fmax(mx, __shfl_xor(mx,o));
  if(h==0) red[wave]=mx;
  __syncthreads();
  f64 maxS = fmax(fmax(fmax(red[0],red[1]),fmax(red[2],red[3])),
                  fmax(fmax(red[4],red[5]),fmax(red[6],red[7])));
  if(tid<RPB){
    f64 sd = sd_in[gr0+tid];
    lds_sd[tid]=sd;
    f64 v = maxS + sd;
    lds_m[tid] = (v>=0.0)? v : 0.01*v;
  }
  __syncthreads();

  const int yA = wave*2, yB = wave*2+1;
  f64 accA=0.0, accB=0.0;
  f64 wsk0=0.0, wsk1=0.0;   // lane partials: rows wave, 8+wave

  for(int jt=0;jt<16;jt++){
    const int j0 = jt*64;
    const f64* src = h1_in + ((long)batch*NNODES + j0)*HDIM;
#pragma unroll
    for(int k=0;k<4;k++){
      int idx = tid + k*NTHR;  // 2048 double2
      ((double2*)htile)[idx] = ((const double2*)src)[idx];
    }
#pragma unroll
    for(int k=0;k<2;k++){
      int idx = tid + k*NTHR;  // 1024 entries = 16 rows x 64
      int row = idx>>6, jj = idx&63;
      f64 v = sb[j0+jj] + lds_sd[row];
      v = (v>=0.0)? v : 0.01*v;
      f64 e = exp(v - lds_m[row]);
      wbuf[idx] = e;
      if(k==0) wsk0+=e; else wsk1+=e;
    }
    __syncthreads();
    const f64* wb = wbuf + yA*64;
#pragma unroll 4
    for(int jg=0; jg<16; jg++){
      int base = jg*4*64 + h;
      f64 h0 = htile[base], h1v = htile[base+64];
      f64 h2 = htile[base+128], h3 = htile[base+192];
      double2 wa  = *(const double2*)(wb + jg*4);
      double2 wa2 = *(const double2*)(wb + jg*4 + 2);
      double2 wbv = *(const double2*)(wb + 64 + jg*4);
      double2 wb2 = *(const double2*)(wb + 64 + jg*4 + 2);
      accA = fma(wa.x,h0,accA);  accA = fma(wa.y,h1v,accA);
      accA = fma(wa2.x,h2,accA); accA = fma(wa2.y,h3,accA);
      accB = fma(wbv.x,h0,accB); accB = fma(wbv.y,h1v,accB);
      accB = fma(wb2.x,h2,accB); accB = fma(wb2.y,h3,accB);
    }
    __syncthreads();
  }
  // one butterfly per row for ws
  f64 w0 = wredsum64(wsk0), w1 = wredsum64(wsk1);
  if(h==0){ lds_ws[wave]=w0; lds_ws[8+wave]=w1; }
  __syncthreads();
  const long grA = gr0 + yA, grB = gr0 + yB;
  outA = accA/lds_ws[yA] + h1_in[grA*HDIM + h];
  outB = accB/lds_ws[yB] + h1_in[grB*HDIM + h];
}

__global__ __launch_bounds__(NTHR) void kMain(Params p){
  __shared__ __align__(16) f64 htile[64*64];   // 32 KB
  __shared__ __align__(16) f64 wbuf[RPB*64];   // 8 KB
  __shared__ __align__(16) f64 lrow[RPB*64];   // gat-out rows / score staging
  __shared__ __align__(16) f64 lx[RPB*64];     // xi rows / next-h1 rows
  __shared__ __align__(16) f64 lh[RPB*64];     // hnew rows
  __shared__ f64 lds_m[RPB], lds_sd[RPB], lds_ws[RPB];
  __shared__ f64 red[8];

  cg::grid_group grid = cg::this_grid();
  const int tid = threadIdx.x, wave = tid>>6, h = tid&63;
  const int bid = blockIdx.x;
  const int batch = bid>>6;
  const int rloc = (bid&63)*RPB;         // node base within batch (0..1008)
  const long gr0 = (long)batch*NNODES + rloc;
  const int yA = wave*2, yB = wave*2+1;
  const long grA = gr0+yA, grB = gr0+yB;

  // ---- phase 0: weight transpose + initial h1 + scores ----
  {
    int gt = bid*NTHR + tid;
    if(gt < 192*HDIM){
      int row=gt>>6, c=gt&63;
      p.w_ihT[c*192+row]=(f64)p.w_ih[gt];
      p.w_hhT[c*192+row]=(f64)p.w_hh[gt];
    }
    const int nA = rloc+yA, nB = rloc+yB;
    const float* xpA = p.x + ((long)(batch*32+0)*1024 + nA)*6;
    const float* xpB = p.x + ((long)(batch*32+0)*1024 + nB)*6;
    f64 xa = (f64)p.fb[h], xb = (f64)p.fb[h];
#pragma unroll
    for(int f=0;f<6;f++){
      xa += (f64)xpA[f]*(f64)p.fw[f*HDIM+h];
      xb += (f64)xpB[f]*(f64)p.fw[f*HDIM+h];
    }
    lrow[yA*64+h]=xa; lrow[yB*64+h]=xb;
    __syncthreads();
    f64 aA = (f64)p.g_in_b[h], aB = aA;
    for(int c=0;c<HDIM;c++){
      f64 w = (f64)p.g_in_w[c*HDIM+h];
      aA += lrow[yA*64+c]*w;
      aB += lrow[yB*64+c]*w;
    }
    p.h1a[grA*HDIM+h]=aA; p.h1a[grB*HDIM+h]=aB;
    lx[yA*64+h]=aA; lx[yB*64+h]=aB;
    __syncthreads();
    f64 sA1,sA2,sB1,sB2;
    s_twostage64(lx+yA*64, p.g_tr_w,p.g_tr_b,p.g_a, h, sA1,sA2);
    s_twostage64(lx+yB*64, p.g_tr_w,p.g_tr_b,p.g_a, h, sB1,sB2);
    if(h==0){
      p.ssa[grA]=sA1; p.sda[grA]=sA2;
      p.ssa[grB]=sB1; p.sda[grB]=sB2;
    }
  }
  grid.sync();

  for(int s=0;s<31;s++){
    // ---- GAT iter 1: h1a -> h1b (+scores) ----
    {
      f64 outA, outB;
      gat_iter(p.h1a,p.ssa,p.sda, htile,wbuf,lds_m,lds_sd,lds_ws,red,
               tid,wave,h,batch,gr0, outA,outB);
      p.h1b[grA*HDIM+h]=outA; p.h1b[grB*HDIM+h]=outB;
      lrow[yA*64+h]=outA; lrow[yB*64+h]=outB;
      __syncthreads();
      f64 sA1,sA2,sB1,sB2;
      s_twostage64(lrow+yA*64, p.g_tr_w,p.g_tr_b,p.g_a, h, sA1,sA2);
      s_twostage64(lrow+yB*64, p.g_tr_w,p.g_tr_b,p.g_a, h, sB1,sB2);
      if(h==0){
        p.ssb[grA]=sA1; p.sdb[grA]=sA2;
        p.ssb[grB]=sB1; p.sdb[grB]=sB2;
      }
    }
    grid.sync();

    // ---- GAT iter 2 + GRU + (next h1 + scores | FFN head) ----
    {
      f64 outA, outB;
      gat_iter(p.h1b,p.ssb,p.sdb, htile,wbuf,lds_m,lds_sd,lds_ws,red,
               tid,wave,h,batch,gr0, outA,outB);
      lrow[yA*64+h]=outA; lrow[yB*64+h]=outB;
      const bool hasxi = (s>0);
      if(hasxi){
        const int nA = rloc+yA, nB = rloc+yB;
        const float* xpA = p.x + ((long)(batch*32+s)*1024 + nA)*6;
        const float* xpB = p.x + ((long)(batch*32+s)*1024 + nB)*6;
        f64 xa = (f64)p.fb[h], xb = (f64)p.fb[h];
#pragma unroll
        for(int f=0;f<6;f++){
          xa += (f64)xpA[f]*(f64)p.fw[f*HDIM+h];
          xb += (f64)xpB[f]*(f64)p.fw[f*HDIM+h];
        }
        lx[yA*64+h]=xa; lx[yB*64+h]=xb;
      }
      __syncthreads();
      // GRU for rows yA,yB (same c-order as absmax-0 lineage)
#pragma unroll
      for(int q=0;q<2;q++){
        const int y = wave*2+q;
        const f64 gato = (q==0)? outA : outB;
        f64 gi0=(f64)p.b_ih[h], gi1=(f64)p.b_ih[64+h], gi2=(f64)p.b_ih[128+h];
        f64 gh0=(f64)p.b_hh[h], gh1=(f64)p.b_hh[64+h], gh2=(f64)p.b_hh[128+h];
        for(int c=0;c<HDIM;c++){
          f64 o = lrow[y*64+c];
          f64 in = hasxi ? lx[y*64+c] : o;
          gi0 += in*p.w_ihT[c*192+h]; gi1 += in*p.w_ihT[c*192+64+h]; gi2 += in*p.w_ihT[c*192+128+h];
          if(hasxi){
            gh0 += o*p.w_hhT[c*192+h]; gh1 += o*p.w_hhT[c*192+64+h]; gh2 += o*p.w_hhT[c*192+128+h];
          }
        }
        f64 rr = 1.0/(1.0+exp(-(gi0+gh0)));
        f64 zz = 1.0/(1.0+exp(-(gi1+gh1)));
        f64 nn = tanh(gi2 + rr*gh2);
        f64 hn = hasxi ? ((1.0-zz)*nn + zz*gato) : (1.0-zz)*nn;
        lh[y*64+h] = hn;
      }
      __syncthreads();
      if(s<30){
        // next h1 = h_new @ g_in_w + b, + scores
        f64 a1A = (f64)p.g_in_b[h], a1B = a1A;
        for(int c=0;c<HDIM;c++){
          f64 w = (f64)p.g_in_w[c*HDIM+h];
          a1A += lh[yA*64+c]*w;
          a1B += lh[yB*64+c]*w;
        }
        p.h1a[grA*HDIM+h]=a1A; p.h1a[grB*HDIM+h]=a1B;
        lx[yA*64+h]=a1A; lx[yB*64+h]=a1B;
        __syncthreads();
        f64 sA1,sA2,sB1,sB2;
        s_twostage64(lx+yA*64, p.g_tr_w,p.g_tr_b,p.g_a, h, sA1,sA2);
        s_twostage64(lx+yB*64, p.g_tr_w,p.g_tr_b,p.g_a, h, sB1,sB2);
        if(h==0){
          p.ssa[grA]=sA1; p.sda[grA]=sA2;
          p.ssa[grB]=sB1; p.sda[grB]=sB2;
        }
        grid.sync();
      } else {
        // FFN head -> dout
#pragma unroll
        for(int q=0;q<2;q++){
          const int y = wave*2+q;
          const long gr = gr0 + y;
          f64 hid = (f64)p.ffn_b[h];
          for(int c=0;c<HDIM;c++) hid += lh[y*64+c]*(f64)p.ffn_w[c*HDIM+h];
          hid = (hid>=0.0)? hid : 0.01*hid;
          f64 o2 = wredsum64(hid*(f64)p.ffn_ow[h]);
          if(h==0) p.dout[gr] = (float)(o2 + (f64)p.ffn_ob[0]);
        }
      }
    }
  }
}

extern "C" void kernel_launch(void* const* d_in, const int* in_sizes, int n_in,
                              void* d_out, int out_size, void* d_ws, size_t ws_size,
                              hipStream_t stream){
  Params p;
  p.x      = (const float*)d_in[0];
  p.fw     = (const float*)d_in[1];
  p.fb     = (const float*)d_in[2];
  p.g_in_w = (const float*)d_in[3];
  p.g_in_b = (const float*)d_in[4];
  p.g_tr_w = (const float*)d_in[5];
  p.g_tr_b = (const float*)d_in[6];
  p.g_a    = (const float*)d_in[7];
  p.w_ih   = (const float*)d_in[8];
  p.w_hh   = (const float*)d_in[9];
  p.b_ih   = (const float*)d_in[10];
  p.b_hh   = (const float*)d_in[11];
  p.ffn_w  = (const float*)d_in[12];
  p.ffn_b  = (const float*)d_in[13];
  p.ffn_ow = (const float*)d_in[14];
  p.ffn_ob = (const float*)d_in[15];

  f64* ws = (f64*)d_ws;
  p.h1a   = ws;
  p.h1b   = p.h1a + (long)NROWS*HDIM;
  p.ssa   = p.h1b + (long)NROWS*HDIM;
  p.sda   = p.ssa + NROWS;
  p.ssb   = p.sda + NROWS;
  p.sdb   = p.ssb + NROWS;
  p.w_ihT = p.sdb + NROWS;
  p.w_hhT = p.w_ihT + 192*HDIM;
  p.dout  = (float*)d_out;

  void* args[] = { &p };
  hipLaunchCooperativeKernel((void*)kMain, dim3(NBLK), dim3(NTHR), args, 0, stream);
}

// Round 9
// 2399.593 us; speedup vs baseline: 3.2751x; 3.2751x over previous
//
#include <hip/hip_runtime.h>
#include <math.h>

typedef double f64;
#define HDIM 64
#define NNODES 1024
#define NROWS 2048
#define RPB 32              // rows per kAgg block
#define NCH 8               // j-chunks
#define CHJ (NNODES/NCH)    // 128 j per chunk

__device__ __forceinline__ f64 wredsum64(f64 v){
#pragma unroll
  for(int o=32;o>0;o>>=1) v += __shfl_xor(v,o);
  return v;
}

// two-stage score, same op-order as the absmax-0 lineage
__device__ __forceinline__ void s_twostage64(const f64* __restrict__ ldsrow,
    const float* __restrict__ g_tr_w, const float* __restrict__ g_tr_b,
    const float* __restrict__ g_a, int h, f64& s_src, f64& s_dst){
  f64 t = (f64)g_tr_b[h];
  for(int c=0;c<HDIM;c++) t = fma(ldsrow[c], (f64)g_tr_w[c*HDIM+h], t);
  s_src = wredsum64(t*(f64)g_a[h]);
  s_dst = wredsum64(t*(f64)g_a[HDIM+h]);
}

// parallel f64 transpose of GRU weights
__global__ void k_pre(const float* __restrict__ w_ih, const float* __restrict__ w_hh,
                      f64* __restrict__ w_ihT, f64* __restrict__ w_hhT){
  int k = blockIdx.x*256 + threadIdx.x;
  if(k >= 192*HDIM) return;
  int row=k>>6, c=k&63;
  w_ihT[c*192+row]=(f64)w_ih[k];
  w_hhT[c*192+row]=(f64)w_hh[k];
}

// initial h1 + scores. 1 wave/row.
__global__ void k1(const float* __restrict__ x, const float* __restrict__ fw,
                   const float* __restrict__ fb,
                   const float* __restrict__ g_in_w, const float* __restrict__ g_in_b,
                   const float* __restrict__ g_tr_w, const float* __restrict__ g_tr_b,
                   const float* __restrict__ g_a,
                   f64* __restrict__ h1, f64* __restrict__ ssrc, f64* __restrict__ sdst){
  __shared__ f64 lx[4*64];
  __shared__ f64 lt[4*64];
  int wave = threadIdx.x >> 6, h = threadIdx.x & 63;
  int r = blockIdx.x*4 + wave;
  int b = r >> 10, n = r & 1023;
  const float* xp = x + ((long)(b*32 + 0)*1024 + n)*6;
  f64 xh = (f64)fb[h];
#pragma unroll
  for(int f=0;f<6;f++) xh += (f64)xp[f]*(f64)fw[f*HDIM+h];
  lx[wave*64+h] = xh;
  __syncthreads();
  f64 a = (f64)g_in_b[h];
  for(int c=0;c<HDIM;c++) a += lx[wave*64+c]*(f64)g_in_w[c*HDIM+h];
  h1[(long)r*HDIM+h] = a;
  lt[wave*64+h] = a;
  __syncthreads();
  f64 s1,s2;
  s_twostage64(lt+wave*64, g_tr_w,g_tr_b,g_a, h, s1,s2);
  if(h==0){ ssrc[r]=s1; sdst[r]=s2; }
}

// Partial attention aggregation. grid = (NROWS/RPB)*NCH = 512 blocks x 512 thr.
// Block (rg, chunk): 32 rows, j in [chunk*128, +128). 4 rows/thread in the FMA loop.
__global__ __launch_bounds__(512) void kAgg(
    const f64* __restrict__ h1_in, const f64* __restrict__ ss_in,
    const f64* __restrict__ sd_in,
    f64* __restrict__ pacc, f64* __restrict__ pws)
{
  __shared__ __align__(16) f64 htile[64*64];  // 32 KB
  __shared__ __align__(16) f64 wbuf[RPB*64];  // 16 KB
  __shared__ f64 lds_m[RPB];
  __shared__ f64 lds_sd[RPB];
  __shared__ f64 red[8];

  const int tid = threadIdx.x, wave = tid>>6, h = tid&63;
  const int chunk = blockIdx.x & (NCH-1);
  const int rg = blockIdx.x >> 3;           // 0..63 (32 rows each)
  const int batch = rg >> 5;                // 32 rgs/batch
  const long gr0 = (long)batch*NNODES + (long)(rg & 31)*RPB;

  const f64* sb = ss_in + (long)batch*NNODES;
  // batch max of s_src (exact row max via monotonicity)
  f64 mx = -1e300;
  for(int j=tid;j<NNODES;j+=512) mx = fmax(mx, sb[j]);
#pragma unroll
  for(int o=32;o>0;o>>=1) mx = fmax(mx, __shfl_xor(mx,o));
  if(h==0) red[wave]=mx;
  __syncthreads();
  f64 maxS = fmax(fmax(fmax(red[0],red[1]),fmax(red[2],red[3])),
                  fmax(fmax(red[4],red[5]),fmax(red[6],red[7])));
  if(tid<RPB){
    f64 sd = sd_in[gr0+tid];
    lds_sd[tid]=sd;
    f64 v = maxS + sd;
    lds_m[tid] = (v>=0.0)? v : 0.01*v;
  }
  __syncthreads();

  f64 acc0=0.0, acc1=0.0, acc2=0.0, acc3=0.0;   // FMA rows wave*4+0..3
  f64 wsk0=0.0, wsk1=0.0, wsk2=0.0, wsk3=0.0;   // ws lane-partials rows wave+8k

  for(int st=0; st<CHJ/64; st++){
    const int j0 = chunk*CHJ + st*64;
    const f64* src = h1_in + ((long)batch*NNODES + j0)*HDIM;
#pragma unroll
    for(int k=0;k<4;k++){
      int idx = tid + k*512;   // 2048 double2 slots
      ((double2*)htile)[idx] = ((const double2*)src)[idx];
    }
    // W build: entry idx = row*64+jj ; thread covers rows wave+8k (exact op order)
#pragma unroll
    for(int k=0;k<4;k++){
      int idx = tid + k*512;
      int row = idx>>6, jj = idx&63;
      f64 v = sb[j0+jj] + lds_sd[row];
      v = (v>=0.0)? v : 0.01*v;
      f64 e = exp(v - lds_m[row]);
      wbuf[idx] = e;
      if(k==0) wsk0+=e; else if(k==1) wsk1+=e; else if(k==2) wsk2+=e; else wsk3+=e;
    }
    __syncthreads();
    const f64* wb = wbuf + (wave*4)*64;
#pragma unroll 4
    for(int jg=0; jg<16; jg++){
      int base = jg*4*64 + h;
      f64 h0 = htile[base], h1v = htile[base+64];
      f64 h2 = htile[base+128], h3 = htile[base+192];
      double2 wa  = *(const double2*)(wb + jg*4);
      double2 wa2 = *(const double2*)(wb + jg*4 + 2);
      double2 wbv = *(const double2*)(wb + 64 + jg*4);
      double2 wb2 = *(const double2*)(wb + 64 + jg*4 + 2);
      double2 wc  = *(const double2*)(wb + 128 + jg*4);
      double2 wc2 = *(const double2*)(wb + 128 + jg*4 + 2);
      double2 wd  = *(const double2*)(wb + 192 + jg*4);
      double2 wd2 = *(const double2*)(wb + 192 + jg*4 + 2);
      acc0 = fma(wa.x,h0,acc0);  acc0 = fma(wa.y,h1v,acc0);
      acc0 = fma(wa2.x,h2,acc0); acc0 = fma(wa2.y,h3,acc0);
      acc1 = fma(wbv.x,h0,acc1); acc1 = fma(wbv.y,h1v,acc1);
      acc1 = fma(wb2.x,h2,acc1); acc1 = fma(wb2.y,h3,acc1);
      acc2 = fma(wc.x,h0,acc2);  acc2 = fma(wc.y,h1v,acc2);
      acc2 = fma(wc2.x,h2,acc2); acc2 = fma(wc2.y,h3,acc2);
      acc3 = fma(wd.x,h0,acc3);  acc3 = fma(wd.y,h1v,acc3);
      acc3 = fma(wd2.x,h2,acc3); acc3 = fma(wd2.y,h3,acc3);
    }
    __syncthreads();
  }

  const long pbase = (long)chunk*NROWS + gr0;
  pacc[(pbase + wave*4+0)*HDIM + h] = acc0;
  pacc[(pbase + wave*4+1)*HDIM + h] = acc1;
  pacc[(pbase + wave*4+2)*HDIM + h] = acc2;
  pacc[(pbase + wave*4+3)*HDIM + h] = acc3;
  f64 w0 = wredsum64(wsk0), w1 = wredsum64(wsk1);
  f64 w2 = wredsum64(wsk2), w3 = wredsum64(wsk3);
  if(h==0){
    pws[pbase + wave     ] = w0;
    pws[pbase + wave + 8 ] = w1;
    pws[pbase + wave + 16] = w2;
    pws[pbase + wave + 24] = w3;
  }
}

// Combine partials -> gat-iter output + residual; then scores. 1 wave/row.
__global__ void kFin0(const f64* __restrict__ pacc, const f64* __restrict__ pws,
                      const f64* __restrict__ h1_in,
                      const float* __restrict__ g_tr_w, const float* __restrict__ g_tr_b,
                      const float* __restrict__ g_a,
                      f64* __restrict__ h1_out, f64* __restrict__ ss_out, f64* __restrict__ sd_out){
  __shared__ f64 lt[4*64];
  int wave = threadIdx.x>>6, h = threadIdx.x&63;
  long r = blockIdx.x*4 + wave;
  f64 a = 0.0, w = 0.0;
#pragma unroll
  for(int c=0;c<NCH;c++){
    a += pacc[((long)c*NROWS + r)*HDIM + h];
    w += pws[(long)c*NROWS + r];
  }
  f64 out = a/w + h1_in[r*HDIM+h];
  h1_out[r*HDIM+h] = out;
  lt[wave*64+h] = out;
  __syncthreads();
  f64 s1,s2;
  s_twostage64(lt+wave*64, g_tr_w,g_tr_b,g_a, h, s1,s2);
  if(h==0){ ss_out[r]=s1; sd_out[r]=s2; }
}

// Combine -> gat out; GRU; then next h1+scores or FFN head. 1 wave/row.
__global__ void kFin1(const f64* __restrict__ pacc, const f64* __restrict__ pws,
                      const f64* __restrict__ h1_in,
                      const float* __restrict__ x, const float* __restrict__ fw,
                      const float* __restrict__ fb,
                      const f64* __restrict__ w_ihT, const f64* __restrict__ w_hhT,
                      const float* __restrict__ b_ih, const float* __restrict__ b_hh,
                      const float* __restrict__ g_in_w, const float* __restrict__ g_in_b,
                      const float* __restrict__ g_tr_w, const float* __restrict__ g_tr_b,
                      const float* __restrict__ g_a,
                      const float* __restrict__ ffn_w, const float* __restrict__ ffn_b,
                      const float* __restrict__ ffn_ow, const float* __restrict__ ffn_ob,
                      f64* __restrict__ h1_out, f64* __restrict__ ss_out, f64* __restrict__ sd_out,
                      float* __restrict__ out, int step, int is_final){
  __shared__ f64 lo[4*64];
  __shared__ f64 lx[4*64];
  __shared__ f64 lh[4*64];
  int wave = threadIdx.x>>6, h = threadIdx.x&63;
  long r = blockIdx.x*4 + wave;
  int batch = (int)(r>>10), n = (int)(r&1023);
  f64 a = 0.0, w = 0.0;
#pragma unroll
  for(int c=0;c<NCH;c++){
    a += pacc[((long)c*NROWS + r)*HDIM + h];
    w += pws[(long)c*NROWS + r];
  }
  f64 gato = a/w + h1_in[r*HDIM+h];
  lo[wave*64+h] = gato;
  const bool hasxi = (step>0);
  if(hasxi){
    const float* xp = x + ((long)(batch*32 + step)*1024 + n)*6;
    f64 xi = (f64)fb[h];
#pragma unroll
    for(int f=0;f<6;f++) xi += (f64)xp[f]*(f64)fw[f*HDIM+h];
    lx[wave*64+h] = xi;
  }
  __syncthreads();
  f64 gi0=(f64)b_ih[h], gi1=(f64)b_ih[64+h], gi2=(f64)b_ih[128+h];
  f64 gh0=(f64)b_hh[h], gh1=(f64)b_hh[64+h], gh2=(f64)b_hh[128+h];
  for(int c=0;c<HDIM;c++){
    f64 o = lo[wave*64+c];
    f64 in = hasxi ? lx[wave*64+c] : o;
    gi0 += in*w_ihT[c*192+h]; gi1 += in*w_ihT[c*192+64+h]; gi2 += in*w_ihT[c*192+128+h];
    if(hasxi){
      gh0 += o*w_hhT[c*192+h]; gh1 += o*w_hhT[c*192+64+h]; gh2 += o*w_hhT[c*192+128+h];
    }
  }
  f64 rr = 1.0/(1.0+exp(-(gi0+gh0)));
  f64 zz = 1.0/(1.0+exp(-(gi1+gh1)));
  f64 nn = tanh(gi2 + rr*gh2);
  f64 hn = hasxi ? ((1.0-zz)*nn + zz*gato) : (1.0-zz)*nn;
  lh[wave*64+h] = hn;
  __syncthreads();
  if(!is_final){
    f64 a1 = (f64)g_in_b[h];
    for(int c=0;c<HDIM;c++) a1 += lh[wave*64+c]*(f64)g_in_w[c*HDIM+h];
    h1_out[r*HDIM+h] = a1;
    lx[wave*64+h] = a1;
    __syncthreads();
    f64 s1,s2;
    s_twostage64(lx+wave*64, g_tr_w,g_tr_b,g_a, h, s1,s2);
    if(h==0){ ss_out[r]=s1; sd_out[r]=s2; }
  } else {
    f64 hid = (f64)ffn_b[h];
    for(int c=0;c<HDIM;c++) hid += lh[wave*64+c]*(f64)ffn_w[c*HDIM+h];
    hid = (hid>=0.0)? hid : 0.01*hid;
    f64 o2 = wredsum64(hid*(f64)ffn_ow[h]);
    if(h==0) out[r] = (float)(o2 + (f64)ffn_ob[0]);
  }
}

extern "C" void kernel_launch(void* const* d_in, const int* in_sizes, int n_in,
                              void* d_out, int out_size, void* d_ws, size_t ws_size,
                              hipStream_t stream){
  const float* x      = (const float*)d_in[0];
  const float* fc_in_w= (const float*)d_in[1];
  const float* fc_in_b= (const float*)d_in[2];
  const float* g_in_w = (const float*)d_in[3];
  const float* g_in_b = (const float*)d_in[4];
  const float* g_tr_w = (const float*)d_in[5];
  const float* g_tr_b = (const float*)d_in[6];
  const float* g_a    = (const float*)d_in[7];
  const float* w_ih   = (const float*)d_in[8];
  const float* w_hh   = (const float*)d_in[9];
  const float* b_ih   = (const float*)d_in[10];
  const float* b_hh   = (const float*)d_in[11];
  const float* ffn_w  = (const float*)d_in[12];
  const float* ffn_b  = (const float*)d_in[13];
  const float* ffn_ow = (const float*)d_in[14];
  const float* ffn_ob = (const float*)d_in[15];

  f64* h1a   = (f64*)d_ws;
  f64* h1b   = h1a + (long)NROWS*HDIM;
  f64* ssa   = h1b + (long)NROWS*HDIM;
  f64* sda   = ssa + NROWS;
  f64* ssb   = sda + NROWS;
  f64* sdb   = ssb + NROWS;
  f64* w_ihT = sdb + NROWS;
  f64* w_hhT = w_ihT + 192*HDIM;
  f64* pacc  = w_hhT + 192*HDIM;
  f64* pws   = pacc + (long)NCH*NROWS*HDIM;

  float* dout = (float*)d_out;

  k_pre<<<48,256,0,stream>>>(w_ih,w_hh,w_ihT,w_hhT);
  k1<<<NROWS/4,256,0,stream>>>(x, fc_in_w, fc_in_b, g_in_w,g_in_b,
                               g_tr_w,g_tr_b,g_a, h1a,ssa,sda);

  for(int s=0;s<31;s++){
    kAgg<<<(NROWS/RPB)*NCH,512,0,stream>>>(h1a,ssa,sda, pacc,pws);
    kFin0<<<NROWS/4,256,0,stream>>>(pacc,pws,h1a, g_tr_w,g_tr_b,g_a, h1b,ssb,sdb);
    kAgg<<<(NROWS/RPB)*NCH,512,0,stream>>>(h1b,ssb,sdb, pacc,pws);
    kFin1<<<NROWS/4,256,0,stream>>>(pacc,pws,h1b,
                                    x,fc_in_w,fc_in_b,
                                    w_ihT,w_hhT,b_ih,b_hh,
                                    g_in_w,g_in_b, g_tr_w,g_tr_b,g_a,
                                    ffn_w,ffn_b,ffn_ow,ffn_ob,
                                    h1a,ssa,sda, dout, s, (s==30)?1:0);
  }
}